// Round 17
// baseline (174.395 us; speedup 1.0000x reference)
//
#include <hip/hip_runtime.h>

#define N_NODES 100000
#define N_EDGES 1000000
#define D 128
#define H 4
#define Dh 32
#define R 64
#define NEG_SLOPE 0.2f
#define NBLK 98          // ceil(N_NODES/1024)
#define GEMM_BLOCKS 391  // 1564 waves, 4 tiles/wave
#define GEMM_WAVES 1564
#define GEMM_ITERS 4
#define HIST_BLOCKS 977  // ceil(N_EDGES/4/256)

typedef unsigned int uint;
typedef __attribute__((ext_vector_type(8))) short bf16x8;
typedef __attribute__((ext_vector_type(4))) float f32x4;
typedef __attribute__((ext_vector_type(2))) float f32x2;

__device__ __forceinline__ float4 ld4(const float* p) { return *reinterpret_cast<const float4*>(p); }
__device__ __forceinline__ float4 add4(float4 a, float4 b) {
    return make_float4(a.x + b.x, a.y + b.y, a.z + b.z, a.w + b.w);
}
__device__ __forceinline__ float4 lrelu4(float4 v) {
    return make_float4(v.x >= 0.f ? v.x : NEG_SLOPE * v.x,
                       v.y >= 0.f ? v.y : NEG_SLOPE * v.y,
                       v.z >= 0.f ? v.z : NEG_SLOPE * v.z,
                       v.w >= 0.f ? v.w : NEG_SLOPE * v.w);
}
// native exp: v_exp_f32 computes 2^x; exp(x) = 2^(x*log2e). Valid for |x| < ~85.
__device__ __forceinline__ float fexp(float x) {
    return __builtin_amdgcn_exp2f(x * 1.4426950408889634f);
}
__device__ __forceinline__ float4 fexp4(float4 v) {
    return make_float4(fexp(v.x), fexp(v.y), fexp(v.z), fexp(v.w));
}
__device__ __forceinline__ float bl(uint u) { return __uint_as_float(u << 16); }
__device__ __forceinline__ float bh(uint u) { return __uint_as_float(u & 0xFFFF0000u); }
__device__ __forceinline__ unsigned short f2bf(float f) {
    uint u = __float_as_uint(f);
    u += 0x7FFF + ((u >> 16) & 1);
    return (unsigned short)(u >> 16);
}
// permuted row layout: stored position p holds channel col(p) = (p&7)*16 + (p>>3)
// record (16B): {x=bf16(lg0)|bf16(lg1)<<16, y=bf16(lg2)|bf16(lg3)<<16, z=src|(t<<20), w=eid}

// packed-f32x2 multiply-accumulate of 8 channels: acc += (h + r) * alpha[head]
__device__ __forceinline__ void mac8(f32x2 acc[4], uint4 hu, uint4 ru, float4 alj) {
    f32x2 h0 = {bl(hu.x), bh(hu.x)}, r0 = {bl(ru.x), bh(ru.x)};
    f32x2 h1 = {bl(hu.y), bh(hu.y)}, r1 = {bl(ru.y), bh(ru.y)};
    f32x2 h2 = {bl(hu.z), bh(hu.z)}, r2 = {bl(ru.z), bh(ru.z)};
    f32x2 h3 = {bl(hu.w), bh(hu.w)}, r3 = {bl(ru.w), bh(ru.w)};
    f32x2 a0 = {alj.x, alj.x}, a1 = {alj.y, alj.y};
    f32x2 a2 = {alj.z, alj.z}, a3 = {alj.w, alj.w};
    acc[0] += (h0 + r0) * a0;
    acc[1] += (h1 + r1) * a1;
    acc[2] += (h2 + r2) * a2;
    acc[3] += (h3 + r3) * a3;
}

// ---- prep: pack Wt, permuted bf16 rel_emb, a_rel, zero cnt (no deps) ----
__global__ __launch_bounds__(256) void k_prep(const float* __restrict__ W,
                                              const float* __restrict__ rel_emb,
                                              const float* __restrict__ att_rel,
                                              unsigned short* __restrict__ Wt,
                                              unsigned short* __restrict__ relb,
                                              float* __restrict__ a_rel,
                                              int* __restrict__ cnt) {
    int i = blockIdx.x * 256 + threadIdx.x;
    if (i < D * D) {
        int col = i >> 7, k = i & 127;
        Wt[i] = f2bf(W[(long)k * D + col]);
    }
    if (i < R * D) {
        int tt = i >> 7, p = i & 127;
        int col = ((p & 7) << 4) + (p >> 3);
        relb[i] = f2bf(rel_emb[(long)tt * D + col]);
    }
    if (i < R * H) {
        int t = i >> 2, hd = i & 3;
        const float* rp = rel_emb + (long)t * D + hd * Dh;
        const float* ar = att_rel + hd * Dh;
        float s = 0.f;
        #pragma unroll
        for (int j = 0; j < 8; ++j) {
            float4 rv = ld4(rp + j * 4);
            float4 av = ld4(ar + j * 4);
            s += rv.x * av.x + rv.y * av.y + rv.z * av.z + rv.w * av.w;
        }
        a_rel[i] = s;
    }
    if (i < N_NODES) cnt[i] = 0;
}

// ---- fused: MFMA GEMM (blocks < GEMM_BLOCKS, 4 tiles/wave) + dst histogram w/ rank capture ----
__global__ __launch_bounds__(256) void k_gemmhist(const float* __restrict__ x,
                                                  const unsigned short* __restrict__ Wt,
                                                  const float* __restrict__ att_src,
                                                  const float* __restrict__ att_dst,
                                                  const int* __restrict__ ei,
                                                  unsigned short* __restrict__ hb,
                                                  float* __restrict__ a_src, float* __restrict__ a_dst,
                                                  int* __restrict__ cnt, uint* __restrict__ rank) {
    if (blockIdx.x >= GEMM_BLOCKS) {
        int e = ((blockIdx.x - GEMM_BLOCKS) * 256 + threadIdx.x) * 4;
        if (e < N_EDGES) {
            int4 d4 = *reinterpret_cast<const int4*>(ei + N_EDGES + e);
            uint4 r4;
            r4.x = (uint)atomicAdd(cnt + d4.x, 1);
            r4.y = (uint)atomicAdd(cnt + d4.y, 1);
            r4.z = (uint)atomicAdd(cnt + d4.z, 1);
            r4.w = (uint)atomicAdd(cnt + d4.w, 1);
            *reinterpret_cast<uint4*>(rank + e) = r4;
        }
        return;
    }
    const int lane = threadIdx.x & 63;
    const int q  = lane & 15;    // A-row / B-col / D-col within tile
    const int kg = lane >> 4;    // k-group
    int wid = blockIdx.x * 4 + (threadIdx.x >> 6);

    // B-fragments: loaded ONCE per wave, live across the 4-tile loop
    bf16x8 Bf[4][8];
    #pragma unroll
    for (int kt = 0; kt < 4; ++kt)
        #pragma unroll
        for (int ct = 0; ct < 8; ++ct)
            Bf[kt][ct] = *reinterpret_cast<const bf16x8*>(Wt + (ct * 16 + q) * D + kt * 32 + kg * 8);

    #pragma unroll
    for (int it = 0; it < GEMM_ITERS; ++it) {
        int rt = wid + it * GEMM_WAVES;
        if (rt >= N_NODES / 16) break;
        const float* xp = x + (long)(rt * 16 + q) * D + kg * 8;
        bf16x8 Af[4];
        #pragma unroll
        for (int kt = 0; kt < 4; ++kt) {
            float4 v0 = ld4(xp + kt * 32);
            float4 v1 = ld4(xp + kt * 32 + 4);
            bf16x8 a;
            a[0] = (short)f2bf(v0.x); a[1] = (short)f2bf(v0.y);
            a[2] = (short)f2bf(v0.z); a[3] = (short)f2bf(v0.w);
            a[4] = (short)f2bf(v1.x); a[5] = (short)f2bf(v1.y);
            a[6] = (short)f2bf(v1.z); a[7] = (short)f2bf(v1.w);
            Af[kt] = a;
        }
        f32x4 acc[8];
        #pragma unroll
        for (int ct = 0; ct < 8; ++ct) acc[ct] = (f32x4){0.f, 0.f, 0.f, 0.f};
        #pragma unroll
        for (int kt = 0; kt < 4; ++kt)
            #pragma unroll
            for (int ct = 0; ct < 8; ++ct)
                acc[ct] = __builtin_amdgcn_mfma_f32_16x16x32_bf16(Af[kt], Bf[kt][ct], acc[ct], 0, 0, 0);
        #pragma unroll
        for (int r = 0; r < 4; ++r) {
            int orow = rt * 16 + kg * 4 + r;
            unsigned short t0 = f2bf(acc[0][r]), t1 = f2bf(acc[1][r]);
            unsigned short t2 = f2bf(acc[2][r]), t3 = f2bf(acc[3][r]);
            unsigned short t4 = f2bf(acc[4][r]), t5 = f2bf(acc[5][r]);
            unsigned short t6 = f2bf(acc[6][r]), t7 = f2bf(acc[7][r]);
            uint4 u;
            u.x = (uint)t0 | ((uint)t1 << 16);
            u.y = (uint)t2 | ((uint)t3 << 16);
            u.z = (uint)t4 | ((uint)t5 << 16);
            u.w = (uint)t6 | ((uint)t7 << 16);
            *reinterpret_cast<uint4*>(hb + (long)orow * D + q * 8) = u;
        }
        // fused nodeatt epilogue
        float ps[4][4], pd[4][4];   // [r][head]
        #pragma unroll
        for (int r = 0; r < 4; ++r)
            #pragma unroll
            for (int hd = 0; hd < 4; ++hd) { ps[r][hd] = 0.f; pd[r][hd] = 0.f; }
        #pragma unroll
        for (int ct = 0; ct < 8; ++ct) {
            float av = att_src[ct * 16 + q];
            float dv = att_dst[ct * 16 + q];
            #pragma unroll
            for (int r = 0; r < 4; ++r) {
                ps[r][ct >> 1] += acc[ct][r] * av;
                pd[r][ct >> 1] += acc[ct][r] * dv;
            }
        }
        #pragma unroll
        for (int off = 1; off <= 8; off <<= 1) {
            #pragma unroll
            for (int r = 0; r < 4; ++r)
                #pragma unroll
                for (int hd = 0; hd < 4; ++hd) {
                    ps[r][hd] += __shfl_xor(ps[r][hd], off);
                    pd[r][hd] += __shfl_xor(pd[r][hd], off);
                }
        }
        if (q == 0) {
            #pragma unroll
            for (int r = 0; r < 4; ++r) {
                int orow = rt * 16 + kg * 4 + r;
                *reinterpret_cast<float4*>(a_src + (long)orow * H) =
                    make_float4(ps[r][0], ps[r][1], ps[r][2], ps[r][3]);
                *reinterpret_cast<float4*>(a_dst + (long)orow * H) =
                    make_float4(pd[r][0], pd[r][1], pd[r][2], pd[r][3]);
            }
        }
    }
}

// ---- scan stage 1: per-1024-chunk exclusive scan of cnt -> offs, chunk totals ----
__global__ __launch_bounds__(1024) void k_scan1(const int* __restrict__ cnt, int* __restrict__ offs,
                                                int* __restrict__ blksum) {
    __shared__ int s[1024];
    int tid = threadIdx.x;
    int i = blockIdx.x * 1024 + tid;
    int v = (i < N_NODES) ? cnt[i] : 0;
    s[tid] = v;
    __syncthreads();
    #pragma unroll
    for (int off = 1; off < 1024; off <<= 1) {
        int t = (tid >= off) ? s[tid - off] : 0;
        __syncthreads();
        s[tid] += t;
        __syncthreads();
    }
    if (i < N_NODES) offs[i] = s[tid] - v;
    if (tid == 1023) blksum[blockIdx.x] = s[1023];
}

// ---- scan stage 2+3 merged: redundant LDS scan of blksum, add offsets ----
__global__ __launch_bounds__(256) void k_scan3(int* __restrict__ offs, const int* __restrict__ blksum) {
    __shared__ int sb[128];
    int tid = threadIdx.x;
    if (tid < 128) sb[tid] = (tid < NBLK) ? blksum[tid] : 0;
    __syncthreads();
    #pragma unroll
    for (int off = 1; off < 128; off <<= 1) {
        int t = (tid < 128 && tid >= off) ? sb[tid - off] : 0;
        __syncthreads();
        if (tid < 128) sb[tid] += t;
        __syncthreads();
    }
    int i = blockIdx.x * 256 + tid;
    if (i < N_NODES) {
        int b = i >> 10;
        int add = (b == 0) ? 0 : sb[b - 1];
        offs[i] += add;
        if (i == 0) offs[N_NODES] = N_EDGES;
    }
}

// ---- fill CSR: 16B record, atomic-free (pos = offs[dst] + rank[e]), 2 edges/thread ----
__global__ __launch_bounds__(256) void k_fillx(const int* __restrict__ ei, const int* __restrict__ et,
                                               const float* __restrict__ a_src, const float* __restrict__ a_dst,
                                               const float* __restrict__ a_rel,
                                               const int* __restrict__ offs, const uint* __restrict__ rank,
                                               uint4* __restrict__ rec) {
    int e = (blockIdx.x * 256 + threadIdx.x) * 2;
    if (e >= N_EDGES) return;
    int2 s2 = *reinterpret_cast<const int2*>(ei + e);
    int2 d2 = *reinterpret_cast<const int2*>(ei + N_EDGES + e);
    int2 t2 = *reinterpret_cast<const int2*>(et + e);
    uint2 r2 = *reinterpret_cast<const uint2*>(rank + e);
    int srcs[2] = { s2.x, s2.y };
    int dsts[2] = { d2.x, d2.y };
    int ts[2]   = { t2.x, t2.y };
    uint rks[2] = { r2.x, r2.y };
    float4 lg[2];
    int pos[2];
    #pragma unroll
    for (int u = 0; u < 2; ++u) {
        lg[u] = lrelu4(add4(add4(ld4(a_src + (long)srcs[u] * H), ld4(a_dst + (long)dsts[u] * H)),
                            ld4(a_rel + (long)ts[u] * H)));
        pos[u] = offs[dsts[u]] + (int)rks[u];
    }
    #pragma unroll
    for (int u = 0; u < 2; ++u) {
        uint lg01 = (uint)f2bf(lg[u].x) | ((uint)f2bf(lg[u].y) << 16);
        uint lg23 = (uint)f2bf(lg[u].z) | ((uint)f2bf(lg[u].w) << 16);
        rec[pos[u]] = make_uint4(lg01, lg23, (uint)srcs[u] | ((uint)ts[u] << 20), (uint)(e + u));
    }
}

// ---- gather: 32 lanes per node, 2 edges per trip (halves), cross-half reduce;
//      no-max softmax; native exp2; 16B records; packed-LDS slot; pk-f32 math ----
__global__ __launch_bounds__(256) void k_gather(const uint4* __restrict__ rec,
                                                const int* __restrict__ offs,
                                                const unsigned short* __restrict__ hb,
                                                const unsigned short* __restrict__ relb,
                                                float* __restrict__ alphaBuf, float* __restrict__ out) {
    __shared__ float s_rec[8][32][8];   // {al0..3, so, to, pad, pad} per edge slot (32B)
    int tid = threadIdx.x;
    int nid = tid >> 5;      // node slot in block (8 per block)
    int l   = tid & 31;      // lane in 32-lane group
    int hi  = l >> 4;        // half index (0/1)
    int ll  = l & 15;        // lane in half
    int n = blockIdx.x * 8 + nid;
    if (n >= N_NODES) return;
    int start = offs[n], end = offs[n + 1];
    int deg = end - start;

    // ---- phase B: chunk-0 (<=32 edges) in regs; exp directly + sum butterfly over 32 lanes ----
    float4 e0 = make_float4(0.f, 0.f, 0.f, 0.f);
    int so0 = 0, to0 = 0, eid0 = 0;
    bool act0 = l < deg;
    if (act0) {
        uint4 r0 = rec[start + l];
        e0 = fexp4(make_float4(bl(r0.x), bh(r0.x), bl(r0.y), bh(r0.y)));
        so0 = (int)((r0.z & 0xFFFFFu) << 8);
        to0 = (int)((r0.z >> 20) << 8);
        eid0 = (int)r0.w;
    }
    float4 z4 = e0;
    for (int base = start + 32; base < end; base += 32)
        if (base + l < end) {
            uint4 r = rec[base + l];
            z4 = add4(z4, fexp4(make_float4(bl(r.x), bh(r.x), bl(r.y), bh(r.y))));
        }
    #pragma unroll
    for (int off = 1; off <= 16; off <<= 1) {
        float4 o = make_float4(__shfl_xor(z4.x, off), __shfl_xor(z4.y, off),
                               __shfl_xor(z4.z, off), __shfl_xor(z4.w, off));
        z4 = add4(z4, o);
    }
    float4 rz4 = make_float4(1.0f / (z4.x + 1e-16f), 1.0f / (z4.y + 1e-16f),
                             1.0f / (z4.z + 1e-16f), 1.0f / (z4.w + 1e-16f));

    // ---- phase C: alpha finalize + packed LDS slot + 2-edge-per-trip message loop ----
    const int cb = ll * 16;           // byte offset of this lane's 8 bf16 (permuted layout)
    const char* hbase = reinterpret_cast<const char*>(hb);
    const char* rbase = reinterpret_cast<const char*>(relb);
    f32x2 acc[4] = {{0.f, 0.f}, {0.f, 0.f}, {0.f, 0.f}, {0.f, 0.f}};
    for (int base = start; base < end; base += 32) {
        int cntc = end - base; if (cntc > 32) cntc = 32;
        if (l < cntc) {
            float4 ex; int so, to, eid;
            if (base == start) {
                ex = e0; so = so0; to = to0; eid = eid0;
            } else {
                uint4 r = rec[base + l];
                ex = fexp4(make_float4(bl(r.x), bh(r.x), bl(r.y), bh(r.y)));
                so = (int)((r.z & 0xFFFFFu) << 8);
                to = (int)((r.z >> 20) << 8);
                eid = (int)r.w;
            }
            float4 af = make_float4(ex.x * rz4.x, ex.y * rz4.y, ex.z * rz4.z, ex.w * rz4.w);
            *reinterpret_cast<float4*>(&s_rec[nid][l][0]) = af;
            *reinterpret_cast<float2*>(&s_rec[nid][l][4]) =
                make_float2(__int_as_float(so), __int_as_float(to));
            *reinterpret_cast<float4*>(alphaBuf + (long)eid * H) = af;   // final alpha, write-once
        }
        // wave-synchronous: writers and readers are the same wave (lockstep).
        // halves process alternating edges: half hi does edges j+2u+hi.
        int j = 0;
        for (; j + 8 <= cntc; j += 8) {
            uint4 hu[4], ru[4];
            float4 aj[4];
            #pragma unroll
            for (int u = 0; u < 4; ++u) {
                int slot = j + 2 * u + hi;
                aj[u] = *reinterpret_cast<float4*>(&s_rec[nid][slot][0]);
                float2 st = *reinterpret_cast<float2*>(&s_rec[nid][slot][4]);
                hu[u] = *reinterpret_cast<const uint4*>(hbase + __float_as_int(st.x) + cb);
                ru[u] = *reinterpret_cast<const uint4*>(rbase + __float_as_int(st.y) + cb);
            }
            #pragma unroll
            for (int u = 0; u < 4; ++u) mac8(acc, hu[u], ru[u], aj[u]);
        }
        for (; j < cntc; j += 2) {
            int slot = j + hi;
            if (slot < cntc) {
                float4 alj = *reinterpret_cast<float4*>(&s_rec[nid][slot][0]);
                float2 st = *reinterpret_cast<float2*>(&s_rec[nid][slot][4]);
                uint4 hu = *reinterpret_cast<const uint4*>(hbase + __float_as_int(st.x) + cb);
                uint4 ru = *reinterpret_cast<const uint4*>(rbase + __float_as_int(st.y) + cb);
                mac8(acc, hu, ru, alj);
            }
        }
    }
    // cross-half reduction: lane l and l^16 hold partial sums of the same channels
    #pragma unroll
    for (int i = 0; i < 4; ++i) {
        acc[i][0] += __shfl_xor(acc[i][0], 16);
        acc[i][1] += __shfl_xor(acc[i][1], 16);
    }
    // gelu (tanh approx) + de-permuted store (half 0 only): channel of acc[i][k] is (2i+k)*16 + ll
    if (hi == 0) {
        #pragma unroll
        for (int i = 0; i < 4; ++i) {
            #pragma unroll
            for (int k = 0; k < 2; ++k) {
                float xx = acc[i][k];
                float g = 0.5f * xx * (1.0f + tanhf(0.7978845608028654f * (xx + 0.044715f * xx * xx * xx)));
                out[(long)n * D + (2 * i + k) * 16 + ll] = g;
            }
        }
    }
}

extern "C" void kernel_launch(void* const* d_in, const int* in_sizes, int n_in,
                              void* d_out, int out_size, void* d_ws, size_t ws_size,
                              hipStream_t stream) {
    const float* x        = (const float*)d_in[0];
    const float* W        = (const float*)d_in[1];
    const float* rel_emb  = (const float*)d_in[2];
    const float* att_src  = (const float*)d_in[3];
    const float* att_dst  = (const float*)d_in[4];
    const float* att_rel  = (const float*)d_in[5];
    const int*   ei       = (const int*)d_in[6];
    const int*   et       = (const int*)d_in[7];

    float* out      = (float*)d_out;                 // [N, D]
    float* alphaBuf = out + (long)N_NODES * D;       // [E, H] final alpha

    unsigned short* hb   = (unsigned short*)d_ws;               // [N, D] bf16 (permuted rows)
    unsigned short* relb = hb + (long)N_NODES * D;              // [R, D] bf16 (permuted rows)
    unsigned short* Wt   = relb + (long)R * D;                  // [D, D] bf16 (transposed)
    uint4*    rec    = (uint4*)(Wt + (long)D * D);              // [E] packed CSR records (16B/edge)
    float*    a_src  = (float*)(rec + (long)N_EDGES);           // [N, H]
    float*    a_dst  = a_src + (long)N_NODES * H;               // [N, H]
    float*    a_rel  = a_dst + (long)N_NODES * H;               // [R, H]
    int*      cnt    = (int*)(a_rel + R * H);                   // [N]
    int*      offs   = cnt + N_NODES;                           // [N+1]
    int*      blksum = offs + N_NODES + 1;                      // [128]
    uint*     rank   = (uint*)(blksum + 128);                   // [E]

    k_prep<<<(N_NODES + 255) / 256, 256, 0, stream>>>(W, rel_emb, att_rel, Wt, relb, a_rel, cnt);
    k_gemmhist<<<GEMM_BLOCKS + HIST_BLOCKS, 256, 0, stream>>>(x, Wt, att_src, att_dst, ei,
                                                              hb, a_src, a_dst, cnt, rank);
    k_scan1<<<NBLK, 1024, 0, stream>>>(cnt, offs, blksum);
    k_scan3<<<(N_NODES + 255) / 256, 256, 0, stream>>>(offs, blksum);
    k_fillx<<<(N_EDGES / 2 + 255) / 256, 256, 0, stream>>>(ei, et, a_src, a_dst, a_rel,
                                                           offs, rank, rec);
    k_gather<<<(N_NODES + 7) / 8, 256, 0, stream>>>(rec, offs, hb, relb, alphaBuf, out);
}

// Round 18
// 153.505 us; speedup vs baseline: 1.1361x; 1.1361x over previous
//
#include <hip/hip_runtime.h>

#define N_NODES 100000
#define N_EDGES 1000000
#define D 128
#define H 4
#define Dh 32
#define R 64
#define NEG_SLOPE 0.2f
#define NBLK 98          // ceil(N_NODES/1024)
#define GEMM_BLOCKS 391  // 1564 waves, 4 tiles/wave
#define GEMM_WAVES 1564
#define GEMM_ITERS 4
#define HIST_BLOCKS 977  // ceil(N_EDGES/4/256)

typedef unsigned int uint;
typedef __attribute__((ext_vector_type(8))) short bf16x8;
typedef __attribute__((ext_vector_type(4))) float f32x4;
typedef __attribute__((ext_vector_type(2))) float f32x2;

__device__ __forceinline__ float4 ld4(const float* p) { return *reinterpret_cast<const float4*>(p); }
__device__ __forceinline__ float4 add4(float4 a, float4 b) {
    return make_float4(a.x + b.x, a.y + b.y, a.z + b.z, a.w + b.w);
}
__device__ __forceinline__ float4 lrelu4(float4 v) {
    return make_float4(v.x >= 0.f ? v.x : NEG_SLOPE * v.x,
                       v.y >= 0.f ? v.y : NEG_SLOPE * v.y,
                       v.z >= 0.f ? v.z : NEG_SLOPE * v.z,
                       v.w >= 0.f ? v.w : NEG_SLOPE * v.w);
}
// native exp: v_exp_f32 computes 2^x; exp(x) = 2^(x*log2e). Valid for |x| < ~85.
__device__ __forceinline__ float fexp(float x) {
    return __builtin_amdgcn_exp2f(x * 1.4426950408889634f);
}
__device__ __forceinline__ float4 fexp4(float4 v) {
    return make_float4(fexp(v.x), fexp(v.y), fexp(v.z), fexp(v.w));
}
__device__ __forceinline__ float bl(uint u) { return __uint_as_float(u << 16); }
__device__ __forceinline__ float bh(uint u) { return __uint_as_float(u & 0xFFFF0000u); }
__device__ __forceinline__ unsigned short f2bf(float f) {
    uint u = __float_as_uint(f);
    u += 0x7FFF + ((u >> 16) & 1);
    return (unsigned short)(u >> 16);
}
// permuted row layout: stored position p holds channel col(p) = (p&7)*16 + (p>>3)
// record (16B): {x=bf16(lg0)|bf16(lg1)<<16, y=bf16(lg2)|bf16(lg3)<<16, z=src|(t<<20), w=eid}

// packed-f32x2 multiply-accumulate of 8 channels: acc += (h + r) * alpha[head]
__device__ __forceinline__ void mac8(f32x2 acc[4], uint4 hu, uint4 ru, float4 alj) {
    f32x2 h0 = {bl(hu.x), bh(hu.x)}, r0 = {bl(ru.x), bh(ru.x)};
    f32x2 h1 = {bl(hu.y), bh(hu.y)}, r1 = {bl(ru.y), bh(ru.y)};
    f32x2 h2 = {bl(hu.z), bh(hu.z)}, r2 = {bl(ru.z), bh(ru.z)};
    f32x2 h3 = {bl(hu.w), bh(hu.w)}, r3 = {bl(ru.w), bh(ru.w)};
    f32x2 a0 = {alj.x, alj.x}, a1 = {alj.y, alj.y};
    f32x2 a2 = {alj.z, alj.z}, a3 = {alj.w, alj.w};
    acc[0] += (h0 + r0) * a0;
    acc[1] += (h1 + r1) * a1;
    acc[2] += (h2 + r2) * a2;
    acc[3] += (h3 + r3) * a3;
}

// ---- prep: pack Wt, permuted bf16 rel_emb, a_rel, zero cnt (no deps) ----
__global__ __launch_bounds__(256) void k_prep(const float* __restrict__ W,
                                              const float* __restrict__ rel_emb,
                                              const float* __restrict__ att_rel,
                                              unsigned short* __restrict__ Wt,
                                              unsigned short* __restrict__ relb,
                                              float* __restrict__ a_rel,
                                              int* __restrict__ cnt) {
    int i = blockIdx.x * 256 + threadIdx.x;
    if (i < D * D) {
        int col = i >> 7, k = i & 127;
        Wt[i] = f2bf(W[(long)k * D + col]);
    }
    if (i < R * D) {
        int tt = i >> 7, p = i & 127;
        int col = ((p & 7) << 4) + (p >> 3);
        relb[i] = f2bf(rel_emb[(long)tt * D + col]);
    }
    if (i < R * H) {
        int t = i >> 2, hd = i & 3;
        const float* rp = rel_emb + (long)t * D + hd * Dh;
        const float* ar = att_rel + hd * Dh;
        float s = 0.f;
        #pragma unroll
        for (int j = 0; j < 8; ++j) {
            float4 rv = ld4(rp + j * 4);
            float4 av = ld4(ar + j * 4);
            s += rv.x * av.x + rv.y * av.y + rv.z * av.z + rv.w * av.w;
        }
        a_rel[i] = s;
    }
    if (i < N_NODES) cnt[i] = 0;
}

// ---- fused: MFMA GEMM (blocks < GEMM_BLOCKS, 4 tiles/wave) + dst histogram w/ rank capture ----
__global__ __launch_bounds__(256) void k_gemmhist(const float* __restrict__ x,
                                                  const unsigned short* __restrict__ Wt,
                                                  const float* __restrict__ att_src,
                                                  const float* __restrict__ att_dst,
                                                  const int* __restrict__ ei,
                                                  unsigned short* __restrict__ hb,
                                                  float* __restrict__ a_src, float* __restrict__ a_dst,
                                                  int* __restrict__ cnt, uint* __restrict__ rank) {
    if (blockIdx.x >= GEMM_BLOCKS) {
        int e = ((blockIdx.x - GEMM_BLOCKS) * 256 + threadIdx.x) * 4;
        if (e < N_EDGES) {
            int4 d4 = *reinterpret_cast<const int4*>(ei + N_EDGES + e);
            uint4 r4;
            r4.x = (uint)atomicAdd(cnt + d4.x, 1);
            r4.y = (uint)atomicAdd(cnt + d4.y, 1);
            r4.z = (uint)atomicAdd(cnt + d4.z, 1);
            r4.w = (uint)atomicAdd(cnt + d4.w, 1);
            *reinterpret_cast<uint4*>(rank + e) = r4;
        }
        return;
    }
    const int lane = threadIdx.x & 63;
    const int q  = lane & 15;    // A-row / B-col / D-col within tile
    const int kg = lane >> 4;    // k-group
    int wid = blockIdx.x * 4 + (threadIdx.x >> 6);

    // B-fragments: loaded ONCE per wave, live across the 4-tile loop
    bf16x8 Bf[4][8];
    #pragma unroll
    for (int kt = 0; kt < 4; ++kt)
        #pragma unroll
        for (int ct = 0; ct < 8; ++ct)
            Bf[kt][ct] = *reinterpret_cast<const bf16x8*>(Wt + (ct * 16 + q) * D + kt * 32 + kg * 8);

    #pragma unroll
    for (int it = 0; it < GEMM_ITERS; ++it) {
        int rt = wid + it * GEMM_WAVES;
        if (rt >= N_NODES / 16) break;
        const float* xp = x + (long)(rt * 16 + q) * D + kg * 8;
        bf16x8 Af[4];
        #pragma unroll
        for (int kt = 0; kt < 4; ++kt) {
            float4 v0 = ld4(xp + kt * 32);
            float4 v1 = ld4(xp + kt * 32 + 4);
            bf16x8 a;
            a[0] = (short)f2bf(v0.x); a[1] = (short)f2bf(v0.y);
            a[2] = (short)f2bf(v0.z); a[3] = (short)f2bf(v0.w);
            a[4] = (short)f2bf(v1.x); a[5] = (short)f2bf(v1.y);
            a[6] = (short)f2bf(v1.z); a[7] = (short)f2bf(v1.w);
            Af[kt] = a;
        }
        f32x4 acc[8];
        #pragma unroll
        for (int ct = 0; ct < 8; ++ct) acc[ct] = (f32x4){0.f, 0.f, 0.f, 0.f};
        #pragma unroll
        for (int kt = 0; kt < 4; ++kt)
            #pragma unroll
            for (int ct = 0; ct < 8; ++ct)
                acc[ct] = __builtin_amdgcn_mfma_f32_16x16x32_bf16(Af[kt], Bf[kt][ct], acc[ct], 0, 0, 0);
        #pragma unroll
        for (int r = 0; r < 4; ++r) {
            int orow = rt * 16 + kg * 4 + r;
            unsigned short t0 = f2bf(acc[0][r]), t1 = f2bf(acc[1][r]);
            unsigned short t2 = f2bf(acc[2][r]), t3 = f2bf(acc[3][r]);
            unsigned short t4 = f2bf(acc[4][r]), t5 = f2bf(acc[5][r]);
            unsigned short t6 = f2bf(acc[6][r]), t7 = f2bf(acc[7][r]);
            uint4 u;
            u.x = (uint)t0 | ((uint)t1 << 16);
            u.y = (uint)t2 | ((uint)t3 << 16);
            u.z = (uint)t4 | ((uint)t5 << 16);
            u.w = (uint)t6 | ((uint)t7 << 16);
            *reinterpret_cast<uint4*>(hb + (long)orow * D + q * 8) = u;
        }
        // fused nodeatt epilogue
        float ps[4][4], pd[4][4];   // [r][head]
        #pragma unroll
        for (int r = 0; r < 4; ++r)
            #pragma unroll
            for (int hd = 0; hd < 4; ++hd) { ps[r][hd] = 0.f; pd[r][hd] = 0.f; }
        #pragma unroll
        for (int ct = 0; ct < 8; ++ct) {
            float av = att_src[ct * 16 + q];
            float dv = att_dst[ct * 16 + q];
            #pragma unroll
            for (int r = 0; r < 4; ++r) {
                ps[r][ct >> 1] += acc[ct][r] * av;
                pd[r][ct >> 1] += acc[ct][r] * dv;
            }
        }
        #pragma unroll
        for (int off = 1; off <= 8; off <<= 1) {
            #pragma unroll
            for (int r = 0; r < 4; ++r)
                #pragma unroll
                for (int hd = 0; hd < 4; ++hd) {
                    ps[r][hd] += __shfl_xor(ps[r][hd], off);
                    pd[r][hd] += __shfl_xor(pd[r][hd], off);
                }
        }
        if (q == 0) {
            #pragma unroll
            for (int r = 0; r < 4; ++r) {
                int orow = rt * 16 + kg * 4 + r;
                *reinterpret_cast<float4*>(a_src + (long)orow * H) =
                    make_float4(ps[r][0], ps[r][1], ps[r][2], ps[r][3]);
                *reinterpret_cast<float4*>(a_dst + (long)orow * H) =
                    make_float4(pd[r][0], pd[r][1], pd[r][2], pd[r][3]);
            }
        }
    }
}

// ---- scan stage 1: per-1024-chunk exclusive scan of cnt -> offs, chunk totals ----
__global__ __launch_bounds__(1024) void k_scan1(const int* __restrict__ cnt, int* __restrict__ offs,
                                                int* __restrict__ blksum) {
    __shared__ int s[1024];
    int tid = threadIdx.x;
    int i = blockIdx.x * 1024 + tid;
    int v = (i < N_NODES) ? cnt[i] : 0;
    s[tid] = v;
    __syncthreads();
    #pragma unroll
    for (int off = 1; off < 1024; off <<= 1) {
        int t = (tid >= off) ? s[tid - off] : 0;
        __syncthreads();
        s[tid] += t;
        __syncthreads();
    }
    if (i < N_NODES) offs[i] = s[tid] - v;
    if (tid == 1023) blksum[blockIdx.x] = s[1023];
}

// ---- scan stage 2+3 merged: redundant LDS scan of blksum, add offsets ----
__global__ __launch_bounds__(256) void k_scan3(int* __restrict__ offs, const int* __restrict__ blksum) {
    __shared__ int sb[128];
    int tid = threadIdx.x;
    if (tid < 128) sb[tid] = (tid < NBLK) ? blksum[tid] : 0;
    __syncthreads();
    #pragma unroll
    for (int off = 1; off < 128; off <<= 1) {
        int t = (tid < 128 && tid >= off) ? sb[tid - off] : 0;
        __syncthreads();
        if (tid < 128) sb[tid] += t;
        __syncthreads();
    }
    int i = blockIdx.x * 256 + tid;
    if (i < N_NODES) {
        int b = i >> 10;
        int add = (b == 0) ? 0 : sb[b - 1];
        offs[i] += add;
        if (i == 0) offs[N_NODES] = N_EDGES;
    }
}

// ---- fill CSR: 16B record, atomic-free (pos = offs[dst] + rank[e]), 4 edges/thread ----
__global__ __launch_bounds__(256) void k_fillx(const int* __restrict__ ei, const int* __restrict__ et,
                                               const float* __restrict__ a_src, const float* __restrict__ a_dst,
                                               const float* __restrict__ a_rel,
                                               const int* __restrict__ offs, const uint* __restrict__ rank,
                                               uint4* __restrict__ rec) {
    int e = (blockIdx.x * 256 + threadIdx.x) * 4;
    if (e >= N_EDGES) return;
    int4 s4 = *reinterpret_cast<const int4*>(ei + e);
    int4 d4 = *reinterpret_cast<const int4*>(ei + N_EDGES + e);
    int4 t4 = *reinterpret_cast<const int4*>(et + e);
    uint4 r4 = *reinterpret_cast<const uint4*>(rank + e);
    int srcs[4] = { s4.x, s4.y, s4.z, s4.w };
    int dsts[4] = { d4.x, d4.y, d4.z, d4.w };
    int ts[4]   = { t4.x, t4.y, t4.z, t4.w };
    uint rks[4] = { r4.x, r4.y, r4.z, r4.w };
    float4 lg[4];
    int pos[4];
    #pragma unroll
    for (int u = 0; u < 4; ++u) {
        lg[u] = lrelu4(add4(add4(ld4(a_src + (long)srcs[u] * H), ld4(a_dst + (long)dsts[u] * H)),
                            ld4(a_rel + (long)ts[u] * H)));
        pos[u] = offs[dsts[u]] + (int)rks[u];
    }
    #pragma unroll
    for (int u = 0; u < 4; ++u) {
        uint lg01 = (uint)f2bf(lg[u].x) | ((uint)f2bf(lg[u].y) << 16);
        uint lg23 = (uint)f2bf(lg[u].z) | ((uint)f2bf(lg[u].w) << 16);
        rec[pos[u]] = make_uint4(lg01, lg23, (uint)srcs[u] | ((uint)ts[u] << 20), (uint)(e + u));
    }
}

// ---- gather: one 16-lane group per node; no-max softmax; native exp2;
//      16B records; packed-LDS slot; 4-deep batched message loop; pk-f32 math ----
__global__ __launch_bounds__(256) void k_gather(const uint4* __restrict__ rec,
                                                const int* __restrict__ offs,
                                                const unsigned short* __restrict__ hb,
                                                const unsigned short* __restrict__ relb,
                                                float* __restrict__ alphaBuf, float* __restrict__ out) {
    __shared__ float s_rec[16][16][8];   // {al0..3, so, to, pad, pad} per edge slot (32B)
    int tid = threadIdx.x;
    int nid = tid >> 4;
    int l   = tid & 15;
    int n = blockIdx.x * 16 + nid;
    if (n >= N_NODES) return;
    int start = offs[n], end = offs[n + 1];
    int deg = end - start;

    // ---- phase B: chunk-0 record in regs; exp directly (no max subtraction) + sum butterfly ----
    float4 e0 = make_float4(0.f, 0.f, 0.f, 0.f);
    int so0 = 0, to0 = 0, eid0 = 0;
    bool act0 = l < deg;
    if (act0) {
        uint4 r0 = rec[start + l];
        e0 = fexp4(make_float4(bl(r0.x), bh(r0.x), bl(r0.y), bh(r0.y)));
        so0 = (int)((r0.z & 0xFFFFFu) << 8);
        to0 = (int)((r0.z >> 20) << 8);
        eid0 = (int)r0.w;
    }
    float4 z4 = e0;
    for (int base = start + 16; base < end; base += 16)
        if (base + l < end) {
            uint4 r = rec[base + l];
            z4 = add4(z4, fexp4(make_float4(bl(r.x), bh(r.x), bl(r.y), bh(r.y))));
        }
    #pragma unroll
    for (int off = 1; off <= 8; off <<= 1) {
        float4 o = make_float4(__shfl_xor(z4.x, off), __shfl_xor(z4.y, off),
                               __shfl_xor(z4.z, off), __shfl_xor(z4.w, off));
        z4 = add4(z4, o);
    }
    float4 rz4 = make_float4(1.0f / (z4.x + 1e-16f), 1.0f / (z4.y + 1e-16f),
                             1.0f / (z4.z + 1e-16f), 1.0f / (z4.w + 1e-16f));

    // ---- phase C: alpha finalize + packed LDS slot + 4-deep batched message loop ----
    const int cb = l * 16;            // byte offset of this lane's 8 bf16 (permuted layout)
    const char* hbase = reinterpret_cast<const char*>(hb);
    const char* rbase = reinterpret_cast<const char*>(relb);
    f32x2 acc[4] = {{0.f, 0.f}, {0.f, 0.f}, {0.f, 0.f}, {0.f, 0.f}};
    for (int base = start; base < end; base += 16) {
        int cntc = end - base; if (cntc > 16) cntc = 16;
        if (l < cntc) {
            float4 ex; int so, to, eid;
            if (base == start) {
                ex = e0; so = so0; to = to0; eid = eid0;
            } else {
                uint4 r = rec[base + l];
                ex = fexp4(make_float4(bl(r.x), bh(r.x), bl(r.y), bh(r.y)));
                so = (int)((r.z & 0xFFFFFu) << 8);
                to = (int)((r.z >> 20) << 8);
                eid = (int)r.w;
            }
            float4 af = make_float4(ex.x * rz4.x, ex.y * rz4.y, ex.z * rz4.z, ex.w * rz4.w);
            *reinterpret_cast<float4*>(&s_rec[nid][l][0]) = af;
            *reinterpret_cast<float2*>(&s_rec[nid][l][4]) =
                make_float2(__int_as_float(so), __int_as_float(to));
            *reinterpret_cast<float4*>(alphaBuf + (long)eid * H) = af;   // final alpha, write-once
        }
        // wave-synchronous: writers and readers are the same wave (lockstep)
        int j = 0;
        for (; j + 4 <= cntc; j += 4) {
            uint4 hu[4], ru[4];
            float4 aj[4];
            #pragma unroll
            for (int u = 0; u < 4; ++u) {
                aj[u] = *reinterpret_cast<float4*>(&s_rec[nid][j + u][0]);
                float2 st = *reinterpret_cast<float2*>(&s_rec[nid][j + u][4]);
                hu[u] = *reinterpret_cast<const uint4*>(hbase + __float_as_int(st.x) + cb);
                ru[u] = *reinterpret_cast<const uint4*>(rbase + __float_as_int(st.y) + cb);
            }
            #pragma unroll
            for (int u = 0; u < 4; ++u) mac8(acc, hu[u], ru[u], aj[u]);
        }
        for (; j < cntc; ++j) {
            float4 alj = *reinterpret_cast<float4*>(&s_rec[nid][j][0]);
            float2 st = *reinterpret_cast<float2*>(&s_rec[nid][j][4]);
            uint4 hu = *reinterpret_cast<const uint4*>(hbase + __float_as_int(st.x) + cb);
            uint4 ru = *reinterpret_cast<const uint4*>(rbase + __float_as_int(st.y) + cb);
            mac8(acc, hu, ru, alj);
        }
    }
    // gelu (tanh approx) + de-permuted store: channel of acc[i][k] is (2i+k)*16 + l
    #pragma unroll
    for (int i = 0; i < 4; ++i) {
        #pragma unroll
        for (int k = 0; k < 2; ++k) {
            float xx = acc[i][k];
            float g = 0.5f * xx * (1.0f + tanhf(0.7978845608028654f * (xx + 0.044715f * xx * xx * xx)));
            out[(long)n * D + (2 * i + k) * 16 + l] = g;
        }
    }
}

extern "C" void kernel_launch(void* const* d_in, const int* in_sizes, int n_in,
                              void* d_out, int out_size, void* d_ws, size_t ws_size,
                              hipStream_t stream) {
    const float* x        = (const float*)d_in[0];
    const float* W        = (const float*)d_in[1];
    const float* rel_emb  = (const float*)d_in[2];
    const float* att_src  = (const float*)d_in[3];
    const float* att_dst  = (const float*)d_in[4];
    const float* att_rel  = (const float*)d_in[5];
    const int*   ei       = (const int*)d_in[6];
    const int*   et       = (const int*)d_in[7];

    float* out      = (float*)d_out;                 // [N, D]
    float* alphaBuf = out + (long)N_NODES * D;       // [E, H] final alpha

    unsigned short* hb   = (unsigned short*)d_ws;               // [N, D] bf16 (permuted rows)
    unsigned short* relb = hb + (long)N_NODES * D;              // [R, D] bf16 (permuted rows)
    unsigned short* Wt   = relb + (long)R * D;                  // [D, D] bf16 (transposed)
    uint4*    rec    = (uint4*)(Wt + (long)D * D);              // [E] packed CSR records (16B/edge)
    float*    a_src  = (float*)(rec + (long)N_EDGES);           // [N, H]
    float*    a_dst  = a_src + (long)N_NODES * H;               // [N, H]
    float*    a_rel  = a_dst + (long)N_NODES * H;               // [R, H]
    int*      cnt    = (int*)(a_rel + R * H);                   // [N]
    int*      offs   = cnt + N_NODES;                           // [N+1]
    int*      blksum = offs + N_NODES + 1;                      // [128]
    uint*     rank   = (uint*)(blksum + 128);                   // [E]

    k_prep<<<(N_NODES + 255) / 256, 256, 0, stream>>>(W, rel_emb, att_rel, Wt, relb, a_rel, cnt);
    k_gemmhist<<<GEMM_BLOCKS + HIST_BLOCKS, 256, 0, stream>>>(x, Wt, att_src, att_dst, ei,
                                                              hb, a_src, a_dst, cnt, rank);
    k_scan1<<<NBLK, 1024, 0, stream>>>(cnt, offs, blksum);
    k_scan3<<<(N_NODES + 255) / 256, 256, 0, stream>>>(offs, blksum);
    k_fillx<<<(N_EDGES / 4 + 255) / 256, 256, 0, stream>>>(ei, et, a_src, a_dst, a_rel,
                                                           offs, rank, rec);
    k_gather<<<(N_NODES + 15) / 16, 256, 0, stream>>>(rec, offs, hb, relb, alphaBuf, out);
}